// Round 1
// baseline (144.174 us; speedup 1.0000x reference)
//
#include <hip/hip_runtime.h>

#define NB    8
#define NH    16384
#define NL    2048
#define F_HR  64
#define F_LR  128
#define OUT_COLS 198   // 64 + 3 + 128 + 3

// ---------------------------------------------------------------------------
// Kernel A: per high-res point, argmin of squared distance over its batch's
// 2048 low-res points. Distance evaluation replicates numpy float32 order:
//   d2 = (ph_sq - 2*dot) + pl_sq,  dot = (x*x' + y*y') + z*z'
// with fp contraction OFF so rounding matches the reference bit-for-bit
// (argmin index must match exactly -> gathered features match exactly).
// ---------------------------------------------------------------------------
__global__ __launch_bounds__(256) void knn_kernel(
    const float* __restrict__ pos_hr,   // [NB*NH, 3]
    const float* __restrict__ pos_lr,   // [NB*NL, 3]
    int* __restrict__ out_idx)          // [NB*NH] global low-res row index
{
#pragma clang fp contract(off)
    __shared__ float4 lds[NL];          // 32 KiB: (x, y, z, |p|^2)

    const int blocksPerBatch = NH / 256;              // 64
    const int b = blockIdx.x / blocksPerBatch;
    const int rowInBatch = (blockIdx.x % blocksPerBatch) * 256 + threadIdx.x;

    // cooperative load of this batch's low-res positions into LDS
    const float* pl = pos_lr + (size_t)b * NL * 3;
    for (int j = threadIdx.x; j < NL; j += 256) {
        float x = pl[j * 3 + 0];
        float y = pl[j * 3 + 1];
        float z = pl[j * 3 + 2];
        float sq = (x * x + y * y) + z * z;           // sequential, no fma
        lds[j] = make_float4(x, y, z, sq);
    }
    __syncthreads();

    const int hr = b * NH + rowInBatch;
    const float phx = pos_hr[hr * 3 + 0];
    const float phy = pos_hr[hr * 3 + 1];
    const float phz = pos_hr[hr * 3 + 2];
    const float ph_sq = (phx * phx + phy * phy) + phz * phz;

    // 4 independent accumulator pairs to break the cmp/select dep chain
    float best0 = 3.4e38f, best1 = 3.4e38f, best2 = 3.4e38f, best3 = 3.4e38f;
    int   bi0 = 0, bi1 = 1, bi2 = 2, bi3 = 3;

    for (int j = 0; j < NL; j += 4) {
        float4 c0 = lds[j + 0];
        float4 c1 = lds[j + 1];
        float4 c2 = lds[j + 2];
        float4 c3 = lds[j + 3];
        float dot0 = (phx * c0.x + phy * c0.y) + phz * c0.z;
        float dot1 = (phx * c1.x + phy * c1.y) + phz * c1.z;
        float dot2 = (phx * c2.x + phy * c2.y) + phz * c2.z;
        float dot3 = (phx * c3.x + phy * c3.y) + phz * c3.z;
        float d0 = (ph_sq - 2.0f * dot0) + c0.w;
        float d1 = (ph_sq - 2.0f * dot1) + c1.w;
        float d2 = (ph_sq - 2.0f * dot2) + c2.w;
        float d3 = (ph_sq - 2.0f * dot3) + c3.w;
        if (d0 < best0) { best0 = d0; bi0 = j + 0; }   // strict <: first wins
        if (d1 < best1) { best1 = d1; bi1 = j + 1; }
        if (d2 < best2) { best2 = d2; bi2 = j + 2; }
        if (d3 < best3) { best3 = d3; bi3 = j + 3; }
    }

    // merge with index tiebreak (lowest index wins on exact ties),
    // matching jnp.argmin's first-occurrence semantics
    float best = best0; int bi = bi0;
    if (best1 < best || (best1 == best && bi1 < bi)) { best = best1; bi = bi1; }
    if (best2 < best || (best2 == best && bi2 < bi)) { best = best2; bi = bi2; }
    if (best3 < best || (best3 == best && bi3 < bi)) { best = best3; bi = bi3; }

    out_idx[hr] = b * NL + bi;
}

// ---------------------------------------------------------------------------
// Kernel B: assemble the flat output buffer.
//   region 0: out_x  [NB*NH, 198] = concat(x_hr, pos_hr, x_lr[idx], pos_lr[idx])
//   region 1: zeros  [NB*NH, 3]
//   region 2: batch  [NB*NH] as float (row >> 14 since NH = 2^14)
// ---------------------------------------------------------------------------
__global__ __launch_bounds__(256) void assemble_kernel(
    const float* __restrict__ x_hr,     // [NB*NH, 64]
    const float* __restrict__ pos_hr,   // [NB*NH, 3]
    const float* __restrict__ x_lr,     // [NB*NL, 128]
    const float* __restrict__ pos_lr,   // [NB*NL, 3]
    const int* __restrict__ idx,        // [NB*NH]
    float* __restrict__ out)
{
    const int R0 = NB * NH * OUT_COLS;        // 25,952,256
    const int R1 = R0 + NB * NH * 3;          // 26,345,472
    const int total = R1 + NB * NH;           // 26,476,544

    for (int i = blockIdx.x * blockDim.x + threadIdx.x;
         i < total; i += gridDim.x * blockDim.x) {
        float v;
        if (i < R0) {
            int row = i / OUT_COLS;
            int col = i - row * OUT_COLS;
            if (col < F_HR) {
                v = x_hr[row * F_HR + col];
            } else if (col < F_HR + 3) {
                v = pos_hr[row * 3 + (col - F_HR)];
            } else if (col < F_HR + 3 + F_LR) {
                int l = idx[row];
                v = x_lr[l * F_LR + (col - (F_HR + 3))];
            } else {
                int l = idx[row];
                v = pos_lr[l * 3 + (col - (F_HR + 3 + F_LR))];
            }
        } else if (i < R1) {
            v = 0.0f;
        } else {
            v = (float)((i - R1) >> 14);      // batch index, NH = 2^14
        }
        out[i] = v;
    }
}

extern "C" void kernel_launch(void* const* d_in, const int* in_sizes, int n_in,
                              void* d_out, int out_size, void* d_ws, size_t ws_size,
                              hipStream_t stream) {
    const float* x_hr   = (const float*)d_in[0];
    const float* pos_hr = (const float*)d_in[1];
    // d_in[2] = batch_hr (int32) — unused, batch is contiguous repeats
    const float* x_lr   = (const float*)d_in[3];
    const float* pos_lr = (const float*)d_in[4];
    // d_in[5] = batch_lr (int32) — unused

    int* idx = (int*)d_ws;                    // NB*NH ints = 512 KiB scratch

    knn_kernel<<<dim3(NB * NH / 256), dim3(256), 0, stream>>>(pos_hr, pos_lr, idx);
    assemble_kernel<<<dim3(3072), dim3(256), 0, stream>>>(
        x_hr, pos_hr, x_lr, pos_lr, idx, (float*)d_out);
}

// Round 3
// 101.278 us; speedup vs baseline: 1.4235x; 1.4235x over previous
//
#include <hip/hip_runtime.h>

#define NB    8
#define NH    16384
#define NL    2048
#define F_HR  64
#define F_LR  128
#define OUT_COLS 198   // 64 + 3 + 128 + 3

typedef float vfloat2 __attribute__((ext_vector_type(2)));  // clang vector: OK for nontemporal builtin

// ---------------------------------------------------------------------------
// Kernel A: per high-res point, argmin over its batch's 2048 low-res points.
// Monotone-transformed key: key_j = 0.5*|pl_j|^2 - <ph, pl_j>
//   == (d2_j - |ph|^2)/2 in exact arithmetic -> same argmin as reference d2.
// Evaluated as a 3-FMA chain seeded with half_sq from LDS. R1 evidence
// (all 131072 argmins matched numpy despite different summation order)
// shows min-gaps are robust to ulp-scale rounding perturbations.
// ---------------------------------------------------------------------------
__global__ __launch_bounds__(256) void knn_kernel(
    const float* __restrict__ pos_hr,   // [NB*NH, 3]
    const float* __restrict__ pos_lr,   // [NB*NL, 3]
    int* __restrict__ out_idx)          // [NB*NH] global low-res row index
{
    __shared__ float4 lds[NL];          // 32 KiB: (x, y, z, 0.5*|p|^2)

    const int blocksPerBatch = NH / 256;              // 64
    const int b = blockIdx.x / blocksPerBatch;
    const int rowInBatch = (blockIdx.x % blocksPerBatch) * 256 + threadIdx.x;

    const float* pl = pos_lr + (size_t)b * NL * 3;
    for (int j = threadIdx.x; j < NL; j += 256) {
        float x = pl[j * 3 + 0];
        float y = pl[j * 3 + 1];
        float z = pl[j * 3 + 2];
        lds[j] = make_float4(x, y, z, 0.5f * ((x * x + y * y) + z * z));
    }
    __syncthreads();

    const int hr = b * NH + rowInBatch;
    const float phx = pos_hr[hr * 3 + 0];
    const float phy = pos_hr[hr * 3 + 1];
    const float phz = pos_hr[hr * 3 + 2];

    // 8 independent accumulator pairs -> deep ILP, short dep chains
    float best[8];
    int   bi[8];
#pragma unroll
    for (int k = 0; k < 8; ++k) { best[k] = 3.4e38f; bi[k] = k; }

    for (int j = 0; j < NL; j += 8) {
#pragma unroll
        for (int k = 0; k < 8; ++k) {
            float4 c = lds[j + k];
            // key = half_sq - (phx*cx + phy*cy + phz*cz), 3 FMAs
            float d = fmaf(-phz, c.z, fmaf(-phy, c.y, fmaf(-phx, c.x, c.w)));
            if (d < best[k]) { best[k] = d; bi[k] = j + k; }   // strict <: first wins
        }
    }

    // merge with index tiebreak (lowest index wins on exact key ties)
    float bestv = best[0]; int bestidx = bi[0];
#pragma unroll
    for (int k = 1; k < 8; ++k) {
        if (best[k] < bestv || (best[k] == bestv && bi[k] < bestidx)) {
            bestv = best[k]; bestidx = bi[k];
        }
    }

    out_idx[hr] = b * NL + bestidx;
}

// ---------------------------------------------------------------------------
// Kernel B: assemble flat output, vectorized as float2 units.
// Layout (floats): [0, R0): out_x rows of 198; [R0, R1): zeros; [R1, total): batch.
// R0, R1, total all even; row stride 792 B => every even-col float2 is 8B-aligned.
// ---------------------------------------------------------------------------
__device__ __forceinline__ float out_elem(
    int row, int col,
    const float* __restrict__ x_hr, const float* __restrict__ pos_hr,
    const float* __restrict__ x_lr, const float* __restrict__ pos_lr,
    const int* __restrict__ idx)
{
    if (col < F_HR)            return x_hr[row * F_HR + col];
    if (col < F_HR + 3)        return pos_hr[row * 3 + (col - F_HR)];
    if (col < F_HR + 3 + F_LR) return x_lr[idx[row] * F_LR + (col - (F_HR + 3))];
    return pos_lr[idx[row] * 3 + (col - (F_HR + 3 + F_LR))];
}

__global__ __launch_bounds__(256) void assemble_kernel(
    const float* __restrict__ x_hr,     // [NB*NH, 64]
    const float* __restrict__ pos_hr,   // [NB*NH, 3]
    const float* __restrict__ x_lr,     // [NB*NL, 128]
    const float* __restrict__ pos_lr,   // [NB*NL, 3]
    const int* __restrict__ idx,        // [NB*NH]
    float* __restrict__ out)
{
    const int R0 = NB * NH * OUT_COLS;        // 25,952,256 (even)
    const int R1 = R0 + NB * NH * 3;          // 26,345,472 (even)
    const int P0 = R0 / 2;                    // float2 units in region 0
    const int P1 = R1 / 2;
    const int total2 = (R1 + NB * NH) / 2;    // 13,238,272

    vfloat2* __restrict__ out2 = (vfloat2*)out;

    for (int t = blockIdx.x * blockDim.x + threadIdx.x;
         t < total2; t += gridDim.x * blockDim.x) {
        vfloat2 v;
        if (t < P0) {
            const int row = t / 99;                  // OUT_COLS/2 = 99 float2 per row
            const int col = (t - row * 99) * 2;
            if (col + 1 < F_HR) {
                // both elements in x_hr region, 8B-aligned source
                v = *(const vfloat2*)&x_hr[row * F_HR + col];
            } else if (col >= F_HR + 3 && col + 2 < F_HR + 3 + F_LR) {
                const int l = idx[row];
                const int c = col - (F_HR + 3);
                v.x = x_lr[l * F_LR + c];
                v.y = x_lr[l * F_LR + c + 1];
            } else {
                v.x = out_elem(row, col,     x_hr, pos_hr, x_lr, pos_lr, idx);
                v.y = out_elem(row, col + 1, x_hr, pos_hr, x_lr, pos_lr, idx);
            }
        } else if (t < P1) {
            v.x = 0.0f; v.y = 0.0f;
        } else {
            const int f = 2 * t - R1;                // first element offset in batch region
            v.x = (float)(f >> 14);                  // NH = 2^14
            v.y = (float)((f + 1) >> 14);
        }
        __builtin_nontemporal_store(v, &out2[t]);
    }
}

extern "C" void kernel_launch(void* const* d_in, const int* in_sizes, int n_in,
                              void* d_out, int out_size, void* d_ws, size_t ws_size,
                              hipStream_t stream) {
    const float* x_hr   = (const float*)d_in[0];
    const float* pos_hr = (const float*)d_in[1];
    // d_in[2] = batch_hr (int32) — unused, batch is contiguous repeats
    const float* x_lr   = (const float*)d_in[3];
    const float* pos_lr = (const float*)d_in[4];
    // d_in[5] = batch_lr (int32) — unused

    int* idx = (int*)d_ws;                    // NB*NH ints = 512 KiB scratch

    knn_kernel<<<dim3(NB * NH / 256), dim3(256), 0, stream>>>(pos_hr, pos_lr, idx);
    assemble_kernel<<<dim3(2048), dim3(256), 0, stream>>>(
        x_hr, pos_hr, x_lr, pos_lr, idx, (float*)d_out);
}